// Round 7
// baseline (416.414 us; speedup 1.0000x reference)
//
#include <hip/hip_runtime.h>

// GymNetwork: routed MLP, B=262144, D=128 -> F=80 -> 80 -> 80 -> A=18, G=8 (idx sorted).
// f32 I/O, bf16 MFMA compute (threshold 6e-2 = 8*bf16_eps*max|ref|).
//
// R17: R16 proved the spill was the (512,4) 128-reg cap (WRITE 283->51MB at cap 256)
// but 1 block/CU left the kernel latency-bound (all pipes <20%, occ 20%). Fix both:
// split L1 into TWO 16-row passes (per-pass live set: af 16 + wf 16 + acc 8 ~= 45 arch
// regs, fits the 64-arch half of the 64/64 split at cap 128), keep L2/L3/L4 processing
// BOTH tiles per shared weight-chunk read (the L2-traffic win of the 32-row structure).
// -> __launch_bounds__(512,4): 2 blocks/CU, 4 waves/SIMD, zero spill intended.
// L1 LDS reads double (25->50/slab) but LDS is cheap and well-pipelined at 4 waves/SIMD.

#define B_TOT   262144
#define DDIM    128
#define FDIM    80
#define ADIM    18
#define SH      104    // LDS stride (shorts) for h rows; 208B breaks pow2 bank stride
#define THREADS 512
#define SLAB    256    // rows per block-iteration (8 waves x 32)
#define NSLAB   2      // block rows = 512
#define GRID    (B_TOT / (SLAB * NSLAB))   // 512 blocks = 2/CU (one generation)

// swizzled bf16 weight workspace in d_ws (shorts); 512-short (1KB) chunks, lane-major
#define W1SW    0                       // 200 chunks: (g*25 + ks*5 + ct); ks=4 = b1 col
#define W2SW    102400                  // 15 chunks: (ks*5+ct); k=80 holds b2, 81..95 zero
#define W3SW    110080                  // 15 chunks; k=80 holds b3
#define W4SW    117760                  // 48 chunks: (g*6+ks*2+ct); k=80 holds b4
#define NCHUNK  278
#define WTOT    (NCHUNK * 512)          // 142336 shorts = 284672 bytes

// LDS layout (shorts)
#define LW1     0                       // 25 chunks (current g) = 12800
#define LHB     12800                   // 8 waves x 32 x SH = 26624
#define LDS_SH  39424                   // 78848 B -> 2 blocks/CU (157696 <= 163840)

typedef __attribute__((ext_vector_type(8))) short short8;
typedef __attribute__((ext_vector_type(2))) unsigned int uint2v;
typedef __attribute__((ext_vector_type(4))) float floatx4;
typedef __attribute__((ext_vector_type(2))) float floatx2;

static __device__ __forceinline__ unsigned short f2bf(float f) {
  union { float f; unsigned u; } v; v.f = f;
  unsigned r = v.u + 0x7fffu + ((v.u >> 16) & 1u);   // RNE
  return (unsigned short)(r >> 16);
}
// pack two f32 -> bf16x2 (lo | hi<<16), RNE
static __device__ __forceinline__ unsigned pk2(float a, float b) {
  union { float f; unsigned u; } x, y; x.f = a; y.f = b;
  unsigned ra = x.u + 0x7fffu + ((x.u >> 16) & 1u);
  unsigned rb = y.u + 0x7fffu + ((y.u >> 16) & 1u);
  return (ra >> 16) | (rb & 0xffff0000u);
}
// load 8 consecutive f32 -> one bf16x8 fragment
static __device__ __forceinline__ short8 ldbf8(const float* sp) {
  floatx4 va = *(const floatx4*)(sp);
  floatx4 vb = *(const floatx4*)(sp + 4);
  short8 f;
  unsigned u0 = pk2(va[0], va[1]), u1 = pk2(va[2], va[3]);
  unsigned u2 = pk2(vb[0], vb[1]), u3 = pk2(vb[2], vb[3]);
  f[0] = (short)(u0 & 0xffff); f[1] = (short)(u0 >> 16);
  f[2] = (short)(u1 & 0xffff); f[3] = (short)(u1 >> 16);
  f[4] = (short)(u2 & 0xffff); f[5] = (short)(u2 >> 16);
  f[6] = (short)(u3 & 0xffff); f[7] = (short)(u3 >> 16);
  return f;
}

// ---- prologue: f32 weights -> bf16 swizzled chunks; biases folded into extra-k cols ----
// chunk: ws[chunk*512 + lane*8 + j] = W[n = ct*16 + (lane&15)][k = ks*32 + (lane>>4)*8 + j]
__global__ void convert_weights(const float* __restrict__ W1, const float* __restrict__ b1,
                                const float* __restrict__ W2, const float* __restrict__ W3,
                                const float* __restrict__ W4, const float* __restrict__ b2,
                                const float* __restrict__ b3, const float* __restrict__ b4,
                                unsigned short* __restrict__ ws) {
  int t = blockIdx.x * 256 + threadIdx.x;
  if (t >= WTOT) return;
  int chunk = t >> 9, r = t & 511;
  int lane = r >> 3, j = r & 7;
  int l16 = lane & 15, quad = lane >> 4;
  float val;
  if (chunk < 200) {                              // W1: [G][80][128] + ks=4 bias col
    int g = chunk / 25, rem = chunk % 25, ks = rem / 5, ct = rem % 5;
    int n = ct * 16 + l16, k = ks * 32 + quad * 8 + j;
    val = (ks < 4) ? W1[(g * FDIM + n) * DDIM + k]
                   : ((quad == 0 && j == 0) ? b1[g * FDIM + n] : 0.f);
  } else if (chunk < 215) {                       // W2: 80x80 -> 80x96, k80 = b2[n]
    int c = chunk - 200, ks = c / 5, ct = c % 5;
    int n = ct * 16 + l16, k = ks * 32 + quad * 8 + j;
    val = (k < FDIM) ? W2[n * FDIM + k] : (k == FDIM ? b2[n] : 0.f);
  } else if (chunk < 230) {                       // W3, k80 = b3[n]
    int c = chunk - 215, ks = c / 5, ct = c % 5;
    int n = ct * 16 + l16, k = ks * 32 + quad * 8 + j;
    val = (k < FDIM) ? W3[n * FDIM + k] : (k == FDIM ? b3[n] : 0.f);
  } else {                                        // W4: Gx18x80 -> Gx32x96, k80 = b4[g][n]
    int c = chunk - 230, g = c / 6, rem = c % 6, ks = rem >> 1, ct = rem & 1;
    int n = ct * 16 + l16, k = ks * 32 + quad * 8 + j;
    val = (n < ADIM) ? ((k < FDIM) ? W4[(g * ADIM + n) * FDIM + k]
                                   : (k == FDIM ? b4[g * ADIM + n] : 0.f)) : 0.f;
  }
  ws[t] = f2bf(val);
}

// W1[g] (25 chunks incl. bias col) -> LDS; barrier pair; block-uniform call sites
static __device__ __forceinline__ void stage_game(
    int g, const unsigned short* __restrict__ wsw, unsigned short* smem, int tid)
{
  __syncthreads();                                // all waves done with old W1
  const short8* src = (const short8*)(wsw + W1SW + g * (25 * 512));
  short8* dst = (short8*)(smem + LW1);
#pragma unroll
  for (int i = 0; i < 4; ++i) {
    int t = i * THREADS + tid;
    if (t < 1600) dst[t] = src[t];
  }
  __syncthreads();                                // new W1 visible
}

#define Z4 ((floatx4){0.f, 0.f, 0.f, 0.f})
#define MFMA(a, b, c) __builtin_amdgcn_mfma_f32_16x16x32_bf16((a), (b), (c), 0, 0, 0)

// relu + pack + h-store of one ct's 4-float acc (row ROW of this wave's hbuf)
#define H_STORE(ROW, CT, ACC) {                                            \
    uint2v u_;                                                             \
    u_[0] = pk2(fmaxf((ACC)[0], 0.f), fmaxf((ACC)[1], 0.f));               \
    u_[1] = pk2(fmaxf((ACC)[2], 0.f), fmaxf((ACC)[3], 0.f));               \
    *(uint2v*)(hbuf + (ROW) * SH + (CT) * 16 + quad * 4) = u_;             \
  }

// ---- L1 (single-tile pass): 2-chunk / 1-chunk k-steps, NAMED b-frag ----
#define L1T_STEP2(KS, CT0, CT1, BF) {                                      \
    short8 wf0 = *(const short8*)(smem + LW1 + ((KS) * 5 + (CT0)) * 512 + lane * 8); \
    short8 wf1 = *(const short8*)(smem + LW1 + ((KS) * 5 + (CT1)) * 512 + lane * 8); \
    a0 = MFMA(wf0, (BF), a0);  a1 = MFMA(wf1, (BF), a1);                   \
  }
#define L1T_STEP1(KS, CT, BF) {                                            \
    short8 wf = *(const short8*)(smem + LW1 + ((KS) * 5 + (CT)) * 512 + lane * 8); \
    a0 = MFMA(wf, (BF), a0);                                               \
  }
// one 16-row tile through L1: af live only inside this pass (the R17 reg fix)
#define L1_PASS(SP, MIDX, RB) {                                            \
    const float* sp_ = (SP);                                               \
    short8 af0 = ldbf8(sp_);                                               \
    short8 af1 = ldbf8(sp_ + 32);                                          \
    short8 af2 = ldbf8(sp_ + 64);                                          \
    short8 af3 = ldbf8(sp_ + 96);                                          \
    {                                                                      \
      floatx4 a0 = Z4, a1 = Z4;                                            \
      L1T_STEP2(0, 0, 1, af0) L1T_STEP2(1, 0, 1, af1)                      \
      L1T_STEP2(2, 0, 1, af2) L1T_STEP2(3, 0, 1, af3)                      \
      L1T_STEP2(4, 0, 1, bfrag)                                            \
      if ((MIDX) == g) { H_STORE(RB, 0, a0); H_STORE(RB, 1, a1); }         \
    }                                                                      \
    {                                                                      \
      floatx4 a0 = Z4, a1 = Z4;                                            \
      L1T_STEP2(0, 2, 3, af0) L1T_STEP2(1, 2, 3, af1)                      \
      L1T_STEP2(2, 2, 3, af2) L1T_STEP2(3, 2, 3, af3)                      \
      L1T_STEP2(4, 2, 3, bfrag)                                            \
      if ((MIDX) == g) { H_STORE(RB, 2, a0); H_STORE(RB, 3, a1); }         \
    }                                                                      \
    {                                                                      \
      floatx4 a0 = Z4;                                                     \
      L1T_STEP1(0, 4, af0) L1T_STEP1(1, 4, af1)                            \
      L1T_STEP1(2, 4, af2) L1T_STEP1(3, 4, af3)                            \
      L1T_STEP1(4, 4, bfrag)                                               \
      if ((MIDX) == g) H_STORE(RB, 4, a0);                                 \
    }                                                                      \
  }

// ---- h-frag loads (named; cols 80..95 carry 1.0-pad for bias-in-k) ----
#define LOAD_H()                                                           \
    short8 hA0 = *(const short8*)(hbuf + l16 * SH +  0 + quad * 8);        \
    short8 hA1 = *(const short8*)(hbuf + l16 * SH + 32 + quad * 8);        \
    short8 hA2 = *(const short8*)(hbuf + l16 * SH + 64 + quad * 8);        \
    short8 hB0 = *(const short8*)(hbuf + (16 + l16) * SH +  0 + quad * 8); \
    short8 hB1 = *(const short8*)(hbuf + (16 + l16) * SH + 32 + quad * 8); \
    short8 hB2 = *(const short8*)(hbuf + (16 + l16) * SH + 64 + quad * 8);

// ---- L2/L3: weights from global (WB, 15-chunk stride-5 layout); both tiles ----
#define L23_STEP(WB, KS, CT0, CT1, HA, HB) {                               \
    short8 wf0 = *(const short8*)((WB) + ((KS) * 5 + (CT0)) * 512 + lane * 8); \
    short8 wf1 = *(const short8*)((WB) + ((KS) * 5 + (CT1)) * 512 + lane * 8); \
    aA0 = MFMA(wf0, (HA), aA0);  aB0 = MFMA(wf0, (HB), aB0);               \
    aA1 = MFMA(wf1, (HA), aA1);  aB1 = MFMA(wf1, (HB), aB1);               \
  }
#define L23_TWO(WB, CT0, CT1) {                                            \
    floatx4 aA0 = Z4, aB0 = Z4, aA1 = Z4, aB1 = Z4;                        \
    L23_STEP(WB, 0, CT0, CT1, hA0, hB0)                                    \
    L23_STEP(WB, 1, CT0, CT1, hA1, hB1)                                    \
    L23_STEP(WB, 2, CT0, CT1, hA2, hB2)                                    \
    H_STORE(l16, CT0, aA0);      H_STORE(l16, CT1, aA1);                   \
    H_STORE(16 + l16, CT0, aB0); H_STORE(16 + l16, CT1, aB1);              \
  }
#define L23_ONE_STEP(WB, KS, CT, HA, HB) {                                 \
    short8 wf = *(const short8*)((WB) + ((KS) * 5 + (CT)) * 512 + lane * 8); \
    aA = MFMA(wf, (HA), aA);  aB = MFMA(wf, (HB), aB);                     \
  }
#define L23_ONE(WB, CT) {                                                  \
    floatx4 aA = Z4, aB = Z4;                                              \
    L23_ONE_STEP(WB, 0, CT, hA0, hB0)                                      \
    L23_ONE_STEP(WB, 1, CT, hA1, hB1)                                      \
    L23_ONE_STEP(WB, 2, CT, hA2, hB2)                                      \
    H_STORE(l16, CT, aA);                                                  \
    H_STORE(16 + l16, CT, aB);                                             \
  }

// ---- L4: W4 layout is 6 chunks/game, (ks*2 + ct) — not stride-5 ----
#define L4_STEP(WB, KS, HA, HB) {                                          \
    short8 wf0 = *(const short8*)((WB) + ((KS) * 2 + 0) * 512 + lane * 8); \
    short8 wf1 = *(const short8*)((WB) + ((KS) * 2 + 1) * 512 + lane * 8); \
    aA0 = MFMA(wf0, (HA), aA0);  aB0 = MFMA(wf0, (HB), aB0);               \
    aA1 = MFMA(wf1, (HA), aA1);  aB1 = MFMA(wf1, (HB), aB1);               \
  }

__global__ __launch_bounds__(THREADS, 4) void gym_fused(
    const float* __restrict__ state, const int* __restrict__ idx,
    const unsigned short* __restrict__ wsw, float* __restrict__ out)
{
  __shared__ __align__(16) unsigned short smem[LDS_SH];

  const int tid  = threadIdx.x;
  const int lane = tid & 63;
  const int wv   = tid >> 6;
  const int l16  = lane & 15;
  const int quad = lane >> 4;
  unsigned short* hbuf = smem + LHB + wv * (32 * SH);
  const size_t blk0 = (size_t)blockIdx.x * (SLAB * NSLAB);

  // ---- hbuf pad cols 80..95 for all 32 rows: col80 = 1.0 (bias-in-k), 81..95 = 0 ----
  {
    int row = lane >> 1, grp = lane & 1;          // 32 rows x 2 groups of 8 shorts
    short8 v = (short8){0, 0, 0, 0, 0, 0, 0, 0};
    if (grp == 0) v[0] = (short)0x3F80;           // bf16 1.0 at col 80
    *(short8*)(hbuf + row * SH + 80 + grp * 8) = v;
  }

  // ---- constant B-frag for L1's ks=4 bias chunk: 1.0 at k=128 (quad 0, j 0) ----
  short8 bfrag = (short8){0, 0, 0, 0, 0, 0, 0, 0};
  if (quad == 0) bfrag[0] = (short)0x3F80;

  // ---- initial game (covered by stage_game's barrier pair) ----
  int curr_g = idx[blk0];
  stage_game(curr_g, wsw, smem, tid);

  for (int it = 0; it < NSLAB; ++it) {
    const size_t slab0 = blk0 + (size_t)it * SLAB;
    const size_t trow  = slab0 + wv * 32;         // this wave's 32 rows (2 x 16 tiles)
    const int tg_lo = idx[slab0];
    const int tg_hi = idx[slab0 + SLAB - 1];      // idx sorted
    const int midxA = idx[trow + l16];            // tile-A lane row's game
    const int midxB = idx[trow + 16 + l16];       // tile-B lane row's game

    for (int g = tg_lo; g <= tg_hi; ++g) {        // block-uniform loop (slab range)
      if (g != curr_g) { stage_game(g, wsw, smem, tid); curr_g = g; }

      // ---- L1 as two 16-row passes: af live set confined per pass ----
      const float* spA = state + (trow + l16) * DDIM + quad * 8;
      L1_PASS(spA, midxA, l16)
      L1_PASS(spA + 16 * DDIM, midxB, 16 + l16)

      // ---- L2: both tiles, weights streamed from global (L1/L2-resident) ----
      {
        LOAD_H()
        const unsigned short* wb = wsw + W2SW;
        L23_TWO(wb, 0, 1)
        L23_TWO(wb, 2, 3)
        L23_ONE(wb, 4)
      }
      // ---- L3 ----
      {
        LOAD_H()
        const unsigned short* wb = wsw + W3SW;
        L23_TWO(wb, 0, 1)
        L23_TWO(wb, 2, 3)
        L23_ONE(wb, 4)
      }
      // ---- L4: both tiles share W4 chunk reads; packed float2 out stores ----
      {
        LOAD_H()
        const unsigned short* wb = wsw + W4SW + g * (6 * 512);
        floatx4 aA0 = Z4, aB0 = Z4, aA1 = Z4, aB1 = Z4;
        L4_STEP(wb, 0, hA0, hB0)
        L4_STEP(wb, 1, hA1, hB1)
        L4_STEP(wb, 2, hA2, hB2)
        if (midxA == g) {                          // n = ct*16 + quad*4 + r, valid n<18
          float* op = out + (trow + l16) * ADIM;
          *(floatx2*)(op + quad * 4)     = (floatx2){aA0[0], aA0[1]};
          *(floatx2*)(op + quad * 4 + 2) = (floatx2){aA0[2], aA0[3]};
          if (quad == 0)
            *(floatx2*)(op + 16) = (floatx2){aA1[0], aA1[1]};
        }
        if (midxB == g) {
          float* op = out + (trow + 16 + l16) * ADIM;
          *(floatx2*)(op + quad * 4)     = (floatx2){aB0[0], aB0[1]};
          *(floatx2*)(op + quad * 4 + 2) = (floatx2){aB0[2], aB0[3]};
          if (quad == 0)
            *(floatx2*)(op + 16) = (floatx2){aB1[0], aB1[1]};
        }
      }
    }
  }
}

extern "C" void kernel_launch(void* const* d_in, const int* in_sizes, int n_in,
                              void* d_out, int out_size, void* d_ws, size_t ws_size,
                              hipStream_t stream) {
  const float* state = (const float*)d_in[0];
  const int*   idx   = (const int*)d_in[1];
  const float* W1    = (const float*)d_in[2];
  const float* b1    = (const float*)d_in[3];
  const float* W2    = (const float*)d_in[4];
  const float* b2    = (const float*)d_in[5];
  const float* W3    = (const float*)d_in[6];
  const float* b3    = (const float*)d_in[7];
  const float* W4    = (const float*)d_in[8];
  const float* b4    = (const float*)d_in[9];
  float*       out   = (float*)d_out;
  unsigned short* wsw = (unsigned short*)d_ws;   // 284672 B used

  convert_weights<<<(WTOT + 255) / 256, 256, 0, stream>>>(W1, b1, W2, W3, W4, b2, b3, b4, wsw);
  gym_fused<<<GRID, THREADS, 0, stream>>>(state, idx, wsw, out);
}

// Round 8
// 386.936 us; speedup vs baseline: 1.0762x; 1.0762x over previous
//
#include <hip/hip_runtime.h>

// GymNetwork: routed MLP, B=262144, D=128 -> F=80 -> 80 -> 80 -> A=18, G=8 (idx sorted).
// f32 I/O, bf16 MFMA compute (threshold 6e-2 = 8*bf16_eps*max|ref|).
//
// R18: the 32-row/wave structure is register-infeasible (cap-128 spills in R11-R15/R17;
// cap-256 fits but is latency-bound at 2 waves/SIMD, R16=98.9us). Revert to the PROVEN
// 16-row/wave live-set (~70-85 regs, fits cap 128) and keep only the reg-free wins:
//   (1) bias-in-k for all 4 layers (no b1v regs, no bias adds),
//   (2) W2/W3/W4 streamed from global (66KB, L2-resident) -> LDS drops to 52224 B
//       = 3 blocks/CU (R10 had 2), 5-6 waves/SIMD -> the latency hiding R16 lacked.
// THREADS=512 (8 waves x 16 rows), SLAB=128, NSLAB=2, GRID=1024.

#define B_TOT   262144
#define DDIM    128
#define FDIM    80
#define ADIM    18
#define SH      104    // LDS stride (shorts); 208B = 52 banks -> rows r,r+8 collide only (2-way, free)
#define THREADS 512
#define SLAB    128    // rows per block-iteration (8 waves x 16)
#define NSLAB   2      // block rows = 256
#define GRID    (B_TOT / (SLAB * NSLAB))   // 1024 blocks, ~3/CU resident (LDS-capped)

// swizzled bf16 weight workspace in d_ws (shorts); 512-short (1KB) chunks, lane-major
#define W1SW    0                       // 200 chunks: (g*25 + ks*5 + ct); ks=4 = b1 col
#define W2SW    102400                  // 15 chunks: (ks*5+ct); k=80 holds b2, 81..95 zero
#define W3SW    110080                  // 15 chunks; k=80 holds b3
#define W4SW    117760                  // 48 chunks: (g*6+ks*2+ct); k=80 holds b4
#define NCHUNK  278
#define WTOT    (NCHUNK * 512)          // 142336 shorts = 284672 bytes

// LDS layout (shorts)
#define LW1     0                       // 25 chunks (current g) = 12800
#define LHB     12800                   // 8 waves x 16 x SH = 13312
#define LDS_SH  26112                   // 52224 B -> 3 blocks/CU (156672 <= 163840)

typedef __attribute__((ext_vector_type(8))) short short8;
typedef __attribute__((ext_vector_type(2))) unsigned int uint2v;
typedef __attribute__((ext_vector_type(4))) float floatx4;
typedef __attribute__((ext_vector_type(2))) float floatx2;

static __device__ __forceinline__ unsigned short f2bf(float f) {
  union { float f; unsigned u; } v; v.f = f;
  unsigned r = v.u + 0x7fffu + ((v.u >> 16) & 1u);   // RNE
  return (unsigned short)(r >> 16);
}
// pack two f32 -> bf16x2 (lo | hi<<16), RNE
static __device__ __forceinline__ unsigned pk2(float a, float b) {
  union { float f; unsigned u; } x, y; x.f = a; y.f = b;
  unsigned ra = x.u + 0x7fffu + ((x.u >> 16) & 1u);
  unsigned rb = y.u + 0x7fffu + ((y.u >> 16) & 1u);
  return (ra >> 16) | (rb & 0xffff0000u);
}
// load 8 consecutive f32 -> one bf16x8 fragment
static __device__ __forceinline__ short8 ldbf8(const float* sp) {
  floatx4 va = *(const floatx4*)(sp);
  floatx4 vb = *(const floatx4*)(sp + 4);
  short8 f;
  unsigned u0 = pk2(va[0], va[1]), u1 = pk2(va[2], va[3]);
  unsigned u2 = pk2(vb[0], vb[1]), u3 = pk2(vb[2], vb[3]);
  f[0] = (short)(u0 & 0xffff); f[1] = (short)(u0 >> 16);
  f[2] = (short)(u1 & 0xffff); f[3] = (short)(u1 >> 16);
  f[4] = (short)(u2 & 0xffff); f[5] = (short)(u2 >> 16);
  f[6] = (short)(u3 & 0xffff); f[7] = (short)(u3 >> 16);
  return f;
}

// ---- prologue: f32 weights -> bf16 swizzled chunks; biases folded into extra-k cols ----
// chunk: ws[chunk*512 + lane*8 + j] = W[n = ct*16 + (lane&15)][k = ks*32 + (lane>>4)*8 + j]
__global__ void convert_weights(const float* __restrict__ W1, const float* __restrict__ b1,
                                const float* __restrict__ W2, const float* __restrict__ W3,
                                const float* __restrict__ W4, const float* __restrict__ b2,
                                const float* __restrict__ b3, const float* __restrict__ b4,
                                unsigned short* __restrict__ ws) {
  int t = blockIdx.x * 256 + threadIdx.x;
  if (t >= WTOT) return;
  int chunk = t >> 9, r = t & 511;
  int lane = r >> 3, j = r & 7;
  int l16 = lane & 15, quad = lane >> 4;
  float val;
  if (chunk < 200) {                              // W1: [G][80][128] + ks=4 bias col
    int g = chunk / 25, rem = chunk % 25, ks = rem / 5, ct = rem % 5;
    int n = ct * 16 + l16, k = ks * 32 + quad * 8 + j;
    val = (ks < 4) ? W1[(g * FDIM + n) * DDIM + k]
                   : ((quad == 0 && j == 0) ? b1[g * FDIM + n] : 0.f);
  } else if (chunk < 215) {                       // W2: 80x80 -> 80x96, k80 = b2[n]
    int c = chunk - 200, ks = c / 5, ct = c % 5;
    int n = ct * 16 + l16, k = ks * 32 + quad * 8 + j;
    val = (k < FDIM) ? W2[n * FDIM + k] : (k == FDIM ? b2[n] : 0.f);
  } else if (chunk < 230) {                       // W3, k80 = b3[n]
    int c = chunk - 215, ks = c / 5, ct = c % 5;
    int n = ct * 16 + l16, k = ks * 32 + quad * 8 + j;
    val = (k < FDIM) ? W3[n * FDIM + k] : (k == FDIM ? b3[n] : 0.f);
  } else {                                        // W4: Gx18x80 -> Gx32x96, k80 = b4[g][n]
    int c = chunk - 230, g = c / 6, rem = c % 6, ks = rem >> 1, ct = rem & 1;
    int n = ct * 16 + l16, k = ks * 32 + quad * 8 + j;
    val = (n < ADIM) ? ((k < FDIM) ? W4[(g * ADIM + n) * FDIM + k]
                                   : (k == FDIM ? b4[g * ADIM + n] : 0.f)) : 0.f;
  }
  ws[t] = f2bf(val);
}

// W1[g] (25 chunks incl. bias col) -> LDS; barrier pair; block-uniform call sites
static __device__ __forceinline__ void stage_game(
    int g, const unsigned short* __restrict__ wsw, unsigned short* smem, int tid)
{
  __syncthreads();                                // all waves done with old W1
  const short8* src = (const short8*)(wsw + W1SW + g * (25 * 512));
  short8* dst = (short8*)(smem + LW1);
#pragma unroll
  for (int i = 0; i < 4; ++i) {
    int t = i * THREADS + tid;
    if (t < 1600) dst[t] = src[t];
  }
  __syncthreads();                                // new W1 visible
}

#define Z4 ((floatx4){0.f, 0.f, 0.f, 0.f})
#define MFMA(a, b, c) __builtin_amdgcn_mfma_f32_16x16x32_bf16((a), (b), (c), 0, 0, 0)

// relu + pack + h-store of one ct's 4-float acc (this wave's 16-row hbuf, row l16)
#define H_STORE(CT, ACC) {                                                 \
    uint2v u_;                                                             \
    u_[0] = pk2(fmaxf((ACC)[0], 0.f), fmaxf((ACC)[1], 0.f));               \
    u_[1] = pk2(fmaxf((ACC)[2], 0.f), fmaxf((ACC)[3], 0.f));               \
    *(uint2v*)(hbuf + l16 * SH + (CT) * 16 + quad * 4) = u_;               \
  }

// ---- L1: W1 from LDS; ct-pair chains; ks=4 = bias chunk x bfrag(1.0) ----
#define L1_STEP2(KS, CT0, CT1, BF) {                                       \
    short8 wf0 = *(const short8*)(smem + LW1 + ((KS) * 5 + (CT0)) * 512 + lane * 8); \
    short8 wf1 = *(const short8*)(smem + LW1 + ((KS) * 5 + (CT1)) * 512 + lane * 8); \
    a0 = MFMA(wf0, (BF), a0);  a1 = MFMA(wf1, (BF), a1);                   \
  }
#define L1_PAIR(CT0, CT1) {                                                \
    floatx4 a0 = Z4, a1 = Z4;                                              \
    L1_STEP2(0, CT0, CT1, af0)                                             \
    L1_STEP2(1, CT0, CT1, af1)                                             \
    L1_STEP2(2, CT0, CT1, af2)                                             \
    L1_STEP2(3, CT0, CT1, af3)                                             \
    L1_STEP2(4, CT0, CT1, bfrag)                                           \
    if (midx == g) { H_STORE(CT0, a0); H_STORE(CT1, a1); }                 \
  }
#define L1_LAST() {                                                        \
    floatx4 a0 = Z4;                                                       \
    { short8 wf = *(const short8*)(smem + LW1 + (0 * 5 + 4) * 512 + lane * 8); a0 = MFMA(wf, af0, a0); } \
    { short8 wf = *(const short8*)(smem + LW1 + (1 * 5 + 4) * 512 + lane * 8); a0 = MFMA(wf, af1, a0); } \
    { short8 wf = *(const short8*)(smem + LW1 + (2 * 5 + 4) * 512 + lane * 8); a0 = MFMA(wf, af2, a0); } \
    { short8 wf = *(const short8*)(smem + LW1 + (3 * 5 + 4) * 512 + lane * 8); a0 = MFMA(wf, af3, a0); } \
    { short8 wf = *(const short8*)(smem + LW1 + (4 * 5 + 4) * 512 + lane * 8); a0 = MFMA(wf, bfrag, a0); } \
    if (midx == g) H_STORE(4, a0);                                         \
  }

// ---- h-frag loads (cols 80..95 carry the 1.0-pad for bias-in-k) ----
#define LOAD_H()                                                           \
    short8 h0 = *(const short8*)(hbuf + l16 * SH +  0 + quad * 8);         \
    short8 h1 = *(const short8*)(hbuf + l16 * SH + 32 + quad * 8);         \
    short8 h2 = *(const short8*)(hbuf + l16 * SH + 64 + quad * 8);

// ---- L2/L3: weights from global (WB, 15-chunk stride-5 layout) ----
#define L23_STEP2(WB, KS, CT0, CT1, HF) {                                  \
    short8 wf0 = *(const short8*)((WB) + ((KS) * 5 + (CT0)) * 512 + lane * 8); \
    short8 wf1 = *(const short8*)((WB) + ((KS) * 5 + (CT1)) * 512 + lane * 8); \
    a0 = MFMA(wf0, (HF), a0);  a1 = MFMA(wf1, (HF), a1);                   \
  }
#define L23_PAIR(WB, CT0, CT1) {                                           \
    floatx4 a0 = Z4, a1 = Z4;                                              \
    L23_STEP2(WB, 0, CT0, CT1, h0)                                         \
    L23_STEP2(WB, 1, CT0, CT1, h1)                                         \
    L23_STEP2(WB, 2, CT0, CT1, h2)                                         \
    H_STORE(CT0, a0);  H_STORE(CT1, a1);                                   \
  }
#define L23_LAST(WB) {                                                     \
    floatx4 a0 = Z4;                                                       \
    { short8 wf = *(const short8*)((WB) + (0 * 5 + 4) * 512 + lane * 8); a0 = MFMA(wf, h0, a0); } \
    { short8 wf = *(const short8*)((WB) + (1 * 5 + 4) * 512 + lane * 8); a0 = MFMA(wf, h1, a0); } \
    { short8 wf = *(const short8*)((WB) + (2 * 5 + 4) * 512 + lane * 8); a0 = MFMA(wf, h2, a0); } \
    H_STORE(4, a0);                                                        \
  }

// ---- L4: W4 layout is 6 chunks/game, (ks*2 + ct) ----
#define L4_STEP(WB, KS, HF) {                                              \
    short8 wf0 = *(const short8*)((WB) + ((KS) * 2 + 0) * 512 + lane * 8); \
    short8 wf1 = *(const short8*)((WB) + ((KS) * 2 + 1) * 512 + lane * 8); \
    a0 = MFMA(wf0, (HF), a0);  a1 = MFMA(wf1, (HF), a1);                   \
  }

__global__ __launch_bounds__(THREADS, 4) void gym_fused(
    const float* __restrict__ state, const int* __restrict__ idx,
    const unsigned short* __restrict__ wsw, float* __restrict__ out)
{
  __shared__ __align__(16) unsigned short smem[LDS_SH];

  const int tid  = threadIdx.x;
  const int lane = tid & 63;
  const int wv   = tid >> 6;
  const int l16  = lane & 15;
  const int quad = lane >> 4;
  unsigned short* hbuf = smem + LHB + wv * (16 * SH);
  const size_t blk0 = (size_t)blockIdx.x * (SLAB * NSLAB);

  // ---- hbuf pad cols 80..95 for 16 rows: col80 = 1.0 (bias-in-k), 81..95 = 0 ----
  {
    short8 v = (short8){0, 0, 0, 0, 0, 0, 0, 0};
    if (quad == 0) v[0] = (short)0x3F80;          // bf16 1.0 at col 80
    if (quad < 2) *(short8*)(hbuf + l16 * SH + 80 + quad * 8) = v;
  }

  // ---- constant B-frag for L1's ks=4 bias chunk: 1.0 at k=128 (quad 0, j 0) ----
  short8 bfrag = (short8){0, 0, 0, 0, 0, 0, 0, 0};
  if (quad == 0) bfrag[0] = (short)0x3F80;

  // ---- initial game (covered by stage_game's barrier pair) ----
  int curr_g = idx[blk0];
  stage_game(curr_g, wsw, smem, tid);

  for (int it = 0; it < NSLAB; ++it) {
    const size_t slab0 = blk0 + (size_t)it * SLAB;
    const size_t trow  = slab0 + wv * 16;         // this wave's 16 rows
    const int tg_lo = idx[slab0];
    const int tg_hi = idx[slab0 + SLAB - 1];      // idx sorted
    const int midx  = idx[trow + l16];            // this lane's row's game

    for (int g = tg_lo; g <= tg_hi; ++g) {        // block-uniform loop (slab range)
      if (g != curr_g) { stage_game(g, wsw, smem, tid); curr_g = g; }

      // ---- state B'-fragments: row = l16, k = quad*8+j ----
      const float* sp = state + (trow + l16) * DDIM + quad * 8;
      short8 af0 = ldbf8(sp);
      short8 af1 = ldbf8(sp + 32);
      short8 af2 = ldbf8(sp + 64);
      short8 af3 = ldbf8(sp + 96);

      // ---- L1: ct-pairs; each chain 8 regs acc; bias via ks=4 chunk ----
      L1_PAIR(0, 1)
      L1_PAIR(2, 3)
      L1_LAST()

      // ---- L2: weights streamed from global (L1/L2-resident) ----
      {
        LOAD_H()
        const unsigned short* wb = wsw + W2SW;
        L23_PAIR(wb, 0, 1)
        L23_PAIR(wb, 2, 3)
        L23_LAST(wb)
      }
      // ---- L3 ----
      {
        LOAD_H()
        const unsigned short* wb = wsw + W3SW;
        L23_PAIR(wb, 0, 1)
        L23_PAIR(wb, 2, 3)
        L23_LAST(wb)
      }
      // ---- L4: packed float2 out stores; n = ct*16 + quad*4 + r, valid n<18 ----
      {
        LOAD_H()
        const unsigned short* wb = wsw + W4SW + g * (6 * 512);
        floatx4 a0 = Z4, a1 = Z4;
        L4_STEP(wb, 0, h0)
        L4_STEP(wb, 1, h1)
        L4_STEP(wb, 2, h2)
        if (midx == g) {
          float* op = out + (trow + l16) * ADIM;
          *(floatx2*)(op + quad * 4)     = (floatx2){a0[0], a0[1]};
          *(floatx2*)(op + quad * 4 + 2) = (floatx2){a0[2], a0[3]};
          if (quad == 0)
            *(floatx2*)(op + 16) = (floatx2){a1[0], a1[1]};
        }
      }
    }
  }
}

extern "C" void kernel_launch(void* const* d_in, const int* in_sizes, int n_in,
                              void* d_out, int out_size, void* d_ws, size_t ws_size,
                              hipStream_t stream) {
  const float* state = (const float*)d_in[0];
  const int*   idx   = (const int*)d_in[1];
  const float* W1    = (const float*)d_in[2];
  const float* b1    = (const float*)d_in[3];
  const float* W2    = (const float*)d_in[4];
  const float* b2    = (const float*)d_in[5];
  const float* W3    = (const float*)d_in[6];
  const float* b3    = (const float*)d_in[7];
  const float* W4    = (const float*)d_in[8];
  const float* b4    = (const float*)d_in[9];
  float*       out   = (float*)d_out;
  unsigned short* wsw = (unsigned short*)d_ws;   // 284672 B used

  convert_weights<<<(WTOT + 255) / 256, 256, 0, stream>>>(W1, b1, W2, W3, W4, b2, b3, b4, wsw);
  gym_fused<<<GRID, THREADS, 0, stream>>>(state, idx, wsw, out);
}